// Round 8
// baseline (147.362 us; speedup 1.0000x reference)
//
#include <hip/hip_runtime.h>
#include <stdint.h>

// Problem constants
#define NUM_C 1000
#define NB    4096
#define NCOL  9192          // NB + NUM_C + NO
#define NPAD  9216          // 36 * 256
#define DK    512
#define BM    128
#define BN    256
#define BKB   32            // K-slab bytes per row (32 fp8 elems)
#define INV_T 10.0f

typedef __attribute__((ext_vector_type(4))) float f32x4;

// workspace layout (bytes)
#define OFF_FALL  0u                 // fp8 [NPAD][DK] = 4,718,592 B
#define OFF_CNTP  4718592u           // uint[16][1024] partial hist (targets+pseudo)
#define OFF_CNTTP 4784128u           // uint[16][1024] partial hist (targets only)
#define OFF_S     4849664u           // float[4096]
#define OFF_P     4866048u           // float[4096]  (contiguous after S)

__device__ __forceinline__ void async16(const void* g, void* l) {
  __builtin_amdgcn_global_load_lds((const __attribute__((address_space(1))) void*)g,
                                   (__attribute__((address_space(3))) void*)l,
                                   16, 0, 0);
}

// f32 -> e4m3fn (OCP), software RNE fallback
__device__ __forceinline__ unsigned sw_e4m3(float x) {
  float ax = fabsf(x);
  unsigned s = (__float_as_uint(x) >> 24) & 0x80u;
  if (ax < 0.015625f) {                       // subnormal, quantum 2^-9
    int n = (int)rintf(ax * 512.0f);
    if (n >= 8) return s | 0x08u;
    return s | (unsigned)n;
  }
  if (ax >= 448.0f) return s | 0x7Eu;
  unsigned u = __float_as_uint(ax);
  int ee = (int)(u >> 23) - 127;              // -6..8
  float scale = __uint_as_float((unsigned)(3 - ee + 127) << 23);
  int qv = (int)rintf(ax * scale);            // 8..16
  if (qv == 16) { ee++; qv = 8; }
  return s | (unsigned)(((ee + 7) << 3) | (qv - 8));
}

template <bool HI>
__device__ __forceinline__ int cvt2(float a, float b, int old) {
#if __has_builtin(__builtin_amdgcn_cvt_pk_fp8_f32)
  return __builtin_amdgcn_cvt_pk_fp8_f32(a, b, old, HI);   // HI is a constant here
#else
  unsigned pk = sw_e4m3(a) | (sw_e4m3(b) << 8);
  return HI ? (int)(((unsigned)old & 0x0000FFFFu) | (pk << 16))
            : (int)(((unsigned)old & 0xFFFF0000u) | pk);
#endif
}

// concat f32->fp8 into fall[NPAD][DK]; blocks 0..15: partial histograms; 16..47: zero S/P
__global__ __launch_bounds__(256) void prep_k(const float* __restrict__ centers,
                                              const float* __restrict__ feats,
                                              const float* __restrict__ ood,
                                              const int* __restrict__ targets,
                                              const int* __restrict__ pseudo,
                                              unsigned char* __restrict__ fall,
                                              unsigned* __restrict__ cntP,
                                              unsigned* __restrict__ cntTP,
                                              float* __restrict__ SP) {
  __shared__ unsigned hc[1024];
  __shared__ unsigned hct[1024];
  const int tid = threadIdx.x;

  int idx = blockIdx.x * 256 + tid;      // one 16-elem chunk each; 9216*32 total
  int row = idx >> 5;
  int ck  = (idx & 31) * 16;
  const float* src = nullptr;
  if (row < NB)              src = feats   + (size_t)row * DK + ck;
  else if (row < NB + NUM_C) src = centers + (size_t)(row - NB) * DK + ck;
  else if (row < NCOL)       src = ood     + (size_t)(row - NB - NUM_C) * DK + ck;
  unsigned w[4] = {0u, 0u, 0u, 0u};
  if (src) {
#pragma unroll
    for (int g = 0; g < 4; g++) {
      float4 v0 = *(const float4*)(src + g * 4);
      int p = 0;
      p = cvt2<false>(v0.x, v0.y, p);
      p = cvt2<true>(v0.z, v0.w, p);
      w[g] = (unsigned)p;
    }
  }
  *(uint4*)(fall + (size_t)row * DK + ck) = make_uint4(w[0], w[1], w[2], w[3]);

  if (blockIdx.x < 16) {
    for (int k = tid; k < 1024; k += 256) { hc[k] = 0u; hct[k] = 0u; }
    __syncthreads();
    int i = blockIdx.x * 256 + tid;      // 0..4095
    int t = targets[i];
    atomicAdd(&hc[t], 1u);
    atomicAdd(&hct[t], 1u);
    atomicAdd(&hc[pseudo[i]], 1u);
    __syncthreads();
    for (int k = tid; k < 1024; k += 256) {
      cntP[blockIdx.x * 1024 + k]  = hc[k];
      cntTP[blockIdx.x * 1024 + k] = hct[k];
    }
  } else if (blockIdx.x < 48) {
    SP[(blockIdx.x - 16) * 256 + tid] = 0.0f;   // zeros S[4096] then P[4096]
  }
}

// Fused fp8 GEMM 128x256 tile, swizzled LDS (conflict-free b64 reads) + S/P reduction
__global__ __launch_bounds__(256, 2) void gemm_fused(const unsigned char* __restrict__ fall,
                                                     const int* __restrict__ targets,
                                                     const int* __restrict__ pseudo,
                                                     const unsigned* __restrict__ cntP,
                                                     float* __restrict__ Sacc,
                                                     float* __restrict__ Pacc) {
  __shared__ unsigned char As[BM * BKB];   // 4 KB
  __shared__ unsigned char Bs[BN * BKB];   // 8 KB
  __shared__ int    sLbl[BN];
  __shared__ float  sRw0[BN];
  __shared__ float  sRw1[BN];
  __shared__ int    sTgt[BM];

  const int tid   = threadIdx.x;
  const int nTile = blockIdx.x;   // 36
  const int mTile = blockIdx.y;   // 32
  const int lane  = tid & 63;
  const int wv    = tid >> 6;     // wave 0..3
  const int wm    = wv >> 1;      // row half (64 rows)
  const int wn    = wv & 1;       // col half (128 cols)
  const int q     = lane >> 4;    // k-quad
  const int cIdx  = lane & 15;

  // per-column tables (lbl, 1/w, 1/(w-1)); per-row targets. w = 1 + sum of partials.
  {
    int j = nTile * BN + tid;
    int lbl, tac;
    if (j >= NCOL)         { lbl = -1; tac = -1; }
    else if (j < NB)       { tac = targets[j]; lbl = tac; }
    else if (j < NB+NUM_C) { tac = j - NB;     lbl = tac; }
    else                   { tac = pseudo[j - NB - NUM_C]; lbl = NUM_C; }
    sLbl[tid] = lbl;
    if (tac >= 0) {
      unsigned c = 1u;
#pragma unroll
      for (int b = 0; b < 16; b++) c += cntP[b * 1024 + tac];
      float w = (float)c;
      sRw0[tid] = 1.0f / w;
      sRw1[tid] = 1.0f / (w - 1.0f);  // only selected when a positive exists => w>=2
    } else {
      sRw0[tid] = 0.f;
      sRw1[tid] = 0.f;
    }
    if (tid < BM) sTgt[tid] = targets[mTile * BM + tid];
  }

  f32x4 acc[4][8];
#pragma unroll
  for (int mi = 0; mi < 4; mi++)
#pragma unroll
    for (int ni = 0; ni < 8; ni++)
      acc[mi][ni] = (f32x4){0.f, 0.f, 0.f, 0.f};

  const int aRow0 = mTile * BM;
  const int bRow0 = nTile * BN;

  // Staging: LDS is lane-linear (tid*16); swizzle lives in the global source:
  // slot (row, cs) holds global 16B chunk cg = cs ^ (row&1).
  const int sRow = tid >> 1;                 // 0..127
  const int cg   = (tid & 1) ^ (sRow & 1);
  const unsigned char* gA  = fall + (size_t)(aRow0 + sRow)       * DK + cg * 16;
  const unsigned char* gB0 = fall + (size_t)(bRow0 + sRow)       * DK + cg * 16;
  const unsigned char* gB1 = fall + (size_t)(bRow0 + 128 + sRow) * DK + cg * 16;
  unsigned char* lA  = As + tid * 16;
  unsigned char* lB0 = Bs + tid * 16;
  unsigned char* lB1 = Bs + 4096 + tid * 16;

  // read-side: global chunk cn = q>>1 sits at slot (q>>1) ^ (row&1); row&1 == cIdx&1
  const int fOff = ((((q >> 1) ^ (cIdx & 1)) << 4) | ((q & 1) << 3));

  for (int kt = 0; kt < DK; kt += BKB) {   // 16 iters, kt in bytes
    __syncthreads();
    async16(gA + kt, lA);
    async16(gB0 + kt, lB0);
    async16(gB1 + kt, lB1);
    __syncthreads();

    long long af[4];
    long long bf8[8];
#pragma unroll
    for (int mi = 0; mi < 4; mi++)
      af[mi] = *(const long long*)&As[(wm * 64 + mi * 16 + cIdx) * BKB + fOff];
#pragma unroll
    for (int ni = 0; ni < 8; ni++)
      bf8[ni] = *(const long long*)&Bs[(wn * 128 + ni * 16 + cIdx) * BKB + fOff];
#pragma unroll
    for (int mi = 0; mi < 4; mi++)
#pragma unroll
      for (int ni = 0; ni < 8; ni++)
        acc[mi][ni] = __builtin_amdgcn_mfma_f32_16x16x32_fp8_fp8(af[mi], bf8[ni], acc[mi][ni], 0, 0, 0);
  }

  // Epilogue: l = acc*10; S += exp(l-10) * (diag?0 : pos?1/(w-1) : 1/w); P += pos?l:0
  float vS[16], vP[16];
#pragma unroll
  for (int s = 0; s < 16; s++) { vS[s] = 0.f; vP[s] = 0.f; }

#pragma unroll
  for (int ni = 0; ni < 8; ni++) {
    int jloc = wn * 128 + ni * 16 + cIdx;
    int j    = nTile * BN + jloc;
    int lblj = sLbl[jloc];
    float rw0 = sRw0[jloc], rw1 = sRw1[jloc];
#pragma unroll
    for (int mi = 0; mi < 4; mi++) {
      f32x4 a = acc[mi][ni];
#pragma unroll
      for (int r = 0; r < 4; r++) {
        int iloc = wm * 64 + mi * 16 + q * 4 + r;
        int i    = mTile * BM + iloc;
        int ti   = sTgt[iloc];
        float l  = a[r] * INV_T;
        bool diag = (j == i);
        bool pos  = (lblj == ti) && !diag;
        float rw  = diag ? 0.0f : (pos ? rw1 : rw0);
        float e   = __expf(l - 10.0f) * rw;
        vS[mi * 4 + r] += e;
        vP[mi * 4 + r] += pos ? l : 0.0f;
      }
    }
  }

  // fully-static value-halving butterfly over the 16 cIdx lanes (15 shuffle pairs)
#define RED_STEP(m, s, h)                                        \
  {                                                              \
    float sendS = (cIdx & (m)) ? vS[(s)] : vS[(s) + (h)];        \
    float sendP = (cIdx & (m)) ? vP[(s)] : vP[(s) + (h)];        \
    float rS = __shfl_xor(sendS, (m), 64);                       \
    float rP = __shfl_xor(sendP, (m), 64);                       \
    vS[(s)] = ((cIdx & (m)) ? vS[(s) + (h)] : vS[(s)]) + rS;     \
    vP[(s)] = ((cIdx & (m)) ? vP[(s) + (h)] : vP[(s)]) + rP;     \
  }
  RED_STEP(8, 0, 8) RED_STEP(8, 1, 8) RED_STEP(8, 2, 8) RED_STEP(8, 3, 8)
  RED_STEP(8, 4, 8) RED_STEP(8, 5, 8) RED_STEP(8, 6, 8) RED_STEP(8, 7, 8)
  RED_STEP(4, 0, 4) RED_STEP(4, 1, 4) RED_STEP(4, 2, 4) RED_STEP(4, 3, 4)
  RED_STEP(2, 0, 2) RED_STEP(2, 1, 2)
  RED_STEP(1, 0, 1)
#undef RED_STEP

  {
    int rowLoc = wm * 64 + (cIdx >> 2) * 16 + q * 4 + (cIdx & 3);
    int i = mTile * BM + rowLoc;
    atomicAdd(&Sacc[i], vS[0]);
    atomicAdd(&Pacc[i], vP[0]);
  }
}

// loss = -mean( P/npos - 10 - log S );  npos_i = sum_b cntTP[b][targets[i]]
__global__ __launch_bounds__(256) void finalize_k(const float* __restrict__ S,
                                                  const float* __restrict__ P,
                                                  const int* __restrict__ targets,
                                                  const unsigned* __restrict__ cntTP,
                                                  float* __restrict__ out) {
  __shared__ unsigned ct[1024];
  __shared__ float red[4];
  int tid = threadIdx.x;
  for (int k = tid; k < 1024; k += 256) {
    unsigned c = 0u;
#pragma unroll
    for (int b = 0; b < 16; b++) c += cntTP[b * 1024 + k];
    ct[k] = c;
  }
  __syncthreads();
  float local = 0.f;
  for (int i = tid; i < NB; i += 256) {
    float npos = (float)ct[targets[i]];
    local += P[i] / npos - INV_T - __logf(S[i]);
  }
  for (int m = 1; m < 64; m <<= 1) local += __shfl_xor(local, m, 64);
  if ((tid & 63) == 0) red[tid >> 6] = local;
  __syncthreads();
  if (tid == 0) {
    float t = red[0] + red[1] + red[2] + red[3];
    out[0] = -t / (float)NB;
  }
}

extern "C" void kernel_launch(void* const* d_in, const int* in_sizes, int n_in,
                              void* d_out, int out_size, void* d_ws, size_t ws_size,
                              hipStream_t stream) {
  const float* centers = (const float*)d_in[0];   // [1000][512] f32
  const float* feats   = (const float*)d_in[1];   // [4096][512] f32
  const int*   targets = (const int*)d_in[2];     // [4096] i32
  const float* ood     = (const float*)d_in[3];   // [4096][512] f32
  const int*   pseudo  = (const int*)d_in[4];     // [4096] i32

  char* ws = (char*)d_ws;
  unsigned char* fall  = (unsigned char*)(ws + OFF_FALL);
  unsigned*      cntP  = (unsigned*)(ws + OFF_CNTP);
  unsigned*      cntTP = (unsigned*)(ws + OFF_CNTTP);
  float*         Sacc  = (float*)(ws + OFF_S);
  float*         Pacc  = (float*)(ws + OFF_P);

  prep_k<<<dim3((NPAD * 32) / 256), 256, 0, stream>>>(centers, feats, ood, targets, pseudo,
                                                      fall, cntP, cntTP, Sacc);
  gemm_fused<<<dim3(NPAD / BN, NB / BM), 256, 0, stream>>>(fall, targets, pseudo, cntP, Sacc, Pacc);
  finalize_k<<<1, 256, 0, stream>>>(Sacc, Pacc, targets, cntTP, (float*)d_out);
}

// Round 9
// 139.141 us; speedup vs baseline: 1.0591x; 1.0591x over previous
//
#include <hip/hip_runtime.h>
#include <stdint.h>

// Problem constants
#define NUM_C 1000
#define NB    4096
#define NCOL  9192          // NB + NUM_C + NO
#define NPAD  9216          // 36 * 256
#define DK    512
#define BM    128
#define BN    256
#define BKB   32            // K-slab bytes per row (32 fp8 elems)
#define INV_T 10.0f

typedef __attribute__((ext_vector_type(4))) float f32x4;

// workspace layout (bytes)
#define OFF_FALL  0u                 // fp8 [NPAD][DK] = 4,718,592 B
#define OFF_CNTP  4718592u           // uint[16][1024] partial hist (targets+pseudo)
#define OFF_CNTTP 4784128u           // uint[16][1024] partial hist (targets only)
#define OFF_S     4849664u           // float[4096]
#define OFF_P     4866048u           // float[4096]  (contiguous after S)

__device__ __forceinline__ void async16(const void* g, void* l) {
  __builtin_amdgcn_global_load_lds((const __attribute__((address_space(1))) void*)g,
                                   (__attribute__((address_space(3))) void*)l,
                                   16, 0, 0);
}

// f32 -> e4m3fn (OCP), software RNE fallback
__device__ __forceinline__ unsigned sw_e4m3(float x) {
  float ax = fabsf(x);
  unsigned s = (__float_as_uint(x) >> 24) & 0x80u;
  if (ax < 0.015625f) {                       // subnormal, quantum 2^-9
    int n = (int)rintf(ax * 512.0f);
    if (n >= 8) return s | 0x08u;
    return s | (unsigned)n;
  }
  if (ax >= 448.0f) return s | 0x7Eu;
  unsigned u = __float_as_uint(ax);
  int ee = (int)(u >> 23) - 127;              // -6..8
  float scale = __uint_as_float((unsigned)(3 - ee + 127) << 23);
  int qv = (int)rintf(ax * scale);            // 8..16
  if (qv == 16) { ee++; qv = 8; }
  return s | (unsigned)(((ee + 7) << 3) | (qv - 8));
}

template <bool HI>
__device__ __forceinline__ int cvt2(float a, float b, int old) {
#if __has_builtin(__builtin_amdgcn_cvt_pk_fp8_f32)
  return __builtin_amdgcn_cvt_pk_fp8_f32(a, b, old, HI);   // HI is a constant here
#else
  unsigned pk = sw_e4m3(a) | (sw_e4m3(b) << 8);
  return HI ? (int)(((unsigned)old & 0x0000FFFFu) | (pk << 16))
            : (int)(((unsigned)old & 0xFFFF0000u) | pk);
#endif
}

// concat f32->fp8 into fall[NPAD][DK]; blocks 0..15: partial histograms; 16..47: zero S/P
__global__ __launch_bounds__(256) void prep_k(const float* __restrict__ centers,
                                              const float* __restrict__ feats,
                                              const float* __restrict__ ood,
                                              const int* __restrict__ targets,
                                              const int* __restrict__ pseudo,
                                              unsigned char* __restrict__ fall,
                                              unsigned* __restrict__ cntP,
                                              unsigned* __restrict__ cntTP,
                                              float* __restrict__ SP) {
  __shared__ unsigned hc[1024];
  __shared__ unsigned hct[1024];
  const int tid = threadIdx.x;

  int idx = blockIdx.x * 256 + tid;      // one 16-elem chunk each; 9216*32 total
  int row = idx >> 5;
  int ck  = (idx & 31) * 16;
  const float* src = nullptr;
  if (row < NB)              src = feats   + (size_t)row * DK + ck;
  else if (row < NB + NUM_C) src = centers + (size_t)(row - NB) * DK + ck;
  else if (row < NCOL)       src = ood     + (size_t)(row - NB - NUM_C) * DK + ck;
  unsigned w[4] = {0u, 0u, 0u, 0u};
  if (src) {
#pragma unroll
    for (int g = 0; g < 4; g++) {
      float4 v0 = *(const float4*)(src + g * 4);
      int p = 0;
      p = cvt2<false>(v0.x, v0.y, p);
      p = cvt2<true>(v0.z, v0.w, p);
      w[g] = (unsigned)p;
    }
  }
  *(uint4*)(fall + (size_t)row * DK + ck) = make_uint4(w[0], w[1], w[2], w[3]);

  if (blockIdx.x < 16) {
    for (int k = tid; k < 1024; k += 256) { hc[k] = 0u; hct[k] = 0u; }
    __syncthreads();
    int i = blockIdx.x * 256 + tid;      // 0..4095
    int t = targets[i];
    atomicAdd(&hc[t], 1u);
    atomicAdd(&hct[t], 1u);
    atomicAdd(&hc[pseudo[i]], 1u);
    __syncthreads();
    for (int k = tid; k < 1024; k += 256) {
      cntP[blockIdx.x * 1024 + k]  = hc[k];
      cntTP[blockIdx.x * 1024 + k] = hct[k];
    }
  } else if (blockIdx.x < 48) {
    SP[(blockIdx.x - 16) * 256 + tid] = 0.0f;   // zeros S[4096] then P[4096]
  }
}

// Fused fp8 GEMM 128x256 tile, DOUBLE-BUFFERED LDS (DMA overlaps compute),
// one barrier per K-iter, + S/P reduction epilogue
__global__ __launch_bounds__(256, 2) void gemm_fused(const unsigned char* __restrict__ fall,
                                                     const int* __restrict__ targets,
                                                     const int* __restrict__ pseudo,
                                                     const unsigned* __restrict__ cntP,
                                                     float* __restrict__ Sacc,
                                                     float* __restrict__ Pacc) {
  __shared__ unsigned char As[2][BM * BKB];   // 2 x 4 KB
  __shared__ unsigned char Bs[2][BN * BKB];   // 2 x 8 KB
  __shared__ int    sLbl[BN];
  __shared__ float  sRw0[BN];
  __shared__ float  sRw1[BN];
  __shared__ int    sTgt[BM];

  const int tid   = threadIdx.x;
  const int nTile = blockIdx.x;   // 36
  const int mTile = blockIdx.y;   // 32
  const int lane  = tid & 63;
  const int wv    = tid >> 6;     // wave 0..3
  const int wm    = wv >> 1;      // row half (64 rows)
  const int wn    = wv & 1;       // col half (128 cols)
  const int q     = lane >> 4;    // k-quad
  const int cIdx  = lane & 15;

  const int aRow0 = mTile * BM;
  const int bRow0 = nTile * BN;

  // Staging: LDS lane-linear (tid*16); swizzle in the global source:
  // slot (row, cs) holds global 16B chunk cg = cs ^ (row&1).
  const int sRow = tid >> 1;                 // 0..127
  const int cg   = (tid & 1) ^ (sRow & 1);
  const unsigned char* gA  = fall + (size_t)(aRow0 + sRow)       * DK + cg * 16;
  const unsigned char* gB0 = fall + (size_t)(bRow0 + sRow)       * DK + cg * 16;
  const unsigned char* gB1 = fall + (size_t)(bRow0 + 128 + sRow) * DK + cg * 16;
  const int lOff = tid * 16;

  // prologue: DMA k-slab 0 into buffer 0 (overlaps with table build below)
  async16(gA,        &As[0][lOff]);
  async16(gB0,       &Bs[0][lOff]);
  async16(gB1,       &Bs[0][lOff + 4096]);

  // per-column tables (lbl, 1/w, 1/(w-1)); per-row targets. w = 1 + sum of partials.
  {
    int j = nTile * BN + tid;
    int lbl, tac;
    if (j >= NCOL)         { lbl = -1; tac = -1; }
    else if (j < NB)       { tac = targets[j]; lbl = tac; }
    else if (j < NB+NUM_C) { tac = j - NB;     lbl = tac; }
    else                   { tac = pseudo[j - NB - NUM_C]; lbl = NUM_C; }
    sLbl[tid] = lbl;
    if (tac >= 0) {
      unsigned c = 1u;
#pragma unroll
      for (int b = 0; b < 16; b++) c += cntP[b * 1024 + tac];
      float w = (float)c;
      sRw0[tid] = 1.0f / w;
      sRw1[tid] = 1.0f / (w - 1.0f);  // only selected when a positive exists => w>=2
    } else {
      sRw0[tid] = 0.f;
      sRw1[tid] = 0.f;
    }
    if (tid < BM) sTgt[tid] = targets[mTile * BM + tid];
  }

  f32x4 acc[4][8];
#pragma unroll
  for (int mi = 0; mi < 4; mi++)
#pragma unroll
    for (int ni = 0; ni < 8; ni++)
      acc[mi][ni] = (f32x4){0.f, 0.f, 0.f, 0.f};

  // read-side: global chunk cn = q>>1 sits at slot (q>>1) ^ (row&1); row&1 == cIdx&1
  const int fOff = ((((q >> 1) ^ (cIdx & 1)) << 4) | ((q & 1) << 3));

  __syncthreads();   // tables ready + (auto vmcnt drain) slab 0 landed

#pragma unroll
  for (int it = 0; it < 16; it++) {
    const int cur = it & 1;
    const int nxt = cur ^ 1;
    if (it < 15) {   // prefetch next slab into the other buffer; overlaps MFMA below
      const int kt = (it + 1) * BKB;
      async16(gA + kt,  &As[nxt][lOff]);
      async16(gB0 + kt, &Bs[nxt][lOff]);
      async16(gB1 + kt, &Bs[nxt][lOff + 4096]);
    }

    long long af[4];
    long long bf8[8];
#pragma unroll
    for (int mi = 0; mi < 4; mi++)
      af[mi] = *(const long long*)&As[cur][(wm * 64 + mi * 16 + cIdx) * BKB + fOff];
#pragma unroll
    for (int ni = 0; ni < 8; ni++)
      bf8[ni] = *(const long long*)&Bs[cur][(wn * 128 + ni * 16 + cIdx) * BKB + fOff];
#pragma unroll
    for (int mi = 0; mi < 4; mi++)
#pragma unroll
      for (int ni = 0; ni < 8; ni++)
        acc[mi][ni] = __builtin_amdgcn_mfma_f32_16x16x32_fp8_fp8(af[mi], bf8[ni], acc[mi][ni], 0, 0, 0);

    __syncthreads();  // everyone done reading cur; next-iter DMA (already mostly done) drains here
  }

  // Epilogue: l = acc*10; S += exp(l-10) * (diag?0 : pos?1/(w-1) : 1/w); P += pos?l:0
  float vS[16], vP[16];
#pragma unroll
  for (int s = 0; s < 16; s++) { vS[s] = 0.f; vP[s] = 0.f; }

#pragma unroll
  for (int ni = 0; ni < 8; ni++) {
    int jloc = wn * 128 + ni * 16 + cIdx;
    int j    = nTile * BN + jloc;
    int lblj = sLbl[jloc];
    float rw0 = sRw0[jloc], rw1 = sRw1[jloc];
#pragma unroll
    for (int mi = 0; mi < 4; mi++) {
      f32x4 a = acc[mi][ni];
#pragma unroll
      for (int r = 0; r < 4; r++) {
        int iloc = wm * 64 + mi * 16 + q * 4 + r;
        int i    = mTile * BM + iloc;
        int ti   = sTgt[iloc];
        float l  = a[r] * INV_T;
        bool diag = (j == i);
        bool pos  = (lblj == ti) && !diag;
        float rw  = diag ? 0.0f : (pos ? rw1 : rw0);
        float e   = __expf(l - 10.0f) * rw;
        vS[mi * 4 + r] += e;
        vP[mi * 4 + r] += pos ? l : 0.0f;
      }
    }
  }

  // fully-static value-halving butterfly over the 16 cIdx lanes (15 shuffle pairs)
#define RED_STEP(m, s, h)                                        \
  {                                                              \
    float sendS = (cIdx & (m)) ? vS[(s)] : vS[(s) + (h)];        \
    float sendP = (cIdx & (m)) ? vP[(s)] : vP[(s) + (h)];        \
    float rS = __shfl_xor(sendS, (m), 64);                       \
    float rP = __shfl_xor(sendP, (m), 64);                       \
    vS[(s)] = ((cIdx & (m)) ? vS[(s) + (h)] : vS[(s)]) + rS;     \
    vP[(s)] = ((cIdx & (m)) ? vP[(s) + (h)] : vP[(s)]) + rP;     \
  }
  RED_STEP(8, 0, 8) RED_STEP(8, 1, 8) RED_STEP(8, 2, 8) RED_STEP(8, 3, 8)
  RED_STEP(8, 4, 8) RED_STEP(8, 5, 8) RED_STEP(8, 6, 8) RED_STEP(8, 7, 8)
  RED_STEP(4, 0, 4) RED_STEP(4, 1, 4) RED_STEP(4, 2, 4) RED_STEP(4, 3, 4)
  RED_STEP(2, 0, 2) RED_STEP(2, 1, 2)
  RED_STEP(1, 0, 1)
#undef RED_STEP

  {
    int rowLoc = wm * 64 + (cIdx >> 2) * 16 + q * 4 + (cIdx & 3);
    int i = mTile * BM + rowLoc;
    atomicAdd(&Sacc[i], vS[0]);
    atomicAdd(&Pacc[i], vP[0]);
  }
}

// loss = -mean( P/npos - 10 - log S );  npos_i = sum_b cntTP[b][targets[i]]
__global__ __launch_bounds__(256) void finalize_k(const float* __restrict__ S,
                                                  const float* __restrict__ P,
                                                  const int* __restrict__ targets,
                                                  const unsigned* __restrict__ cntTP,
                                                  float* __restrict__ out) {
  __shared__ unsigned ct[1024];
  __shared__ float red[4];
  int tid = threadIdx.x;
  for (int k = tid; k < 1024; k += 256) {
    unsigned c = 0u;
#pragma unroll
    for (int b = 0; b < 16; b++) c += cntTP[b * 1024 + k];
    ct[k] = c;
  }
  __syncthreads();
  float local = 0.f;
  for (int i = tid; i < NB; i += 256) {
    float npos = (float)ct[targets[i]];
    local += P[i] / npos - INV_T - __logf(S[i]);
  }
  for (int m = 1; m < 64; m <<= 1) local += __shfl_xor(local, m, 64);
  if ((tid & 63) == 0) red[tid >> 6] = local;
  __syncthreads();
  if (tid == 0) {
    float t = red[0] + red[1] + red[2] + red[3];
    out[0] = -t / (float)NB;
  }
}

extern "C" void kernel_launch(void* const* d_in, const int* in_sizes, int n_in,
                              void* d_out, int out_size, void* d_ws, size_t ws_size,
                              hipStream_t stream) {
  const float* centers = (const float*)d_in[0];   // [1000][512] f32
  const float* feats   = (const float*)d_in[1];   // [4096][512] f32
  const int*   targets = (const int*)d_in[2];     // [4096] i32
  const float* ood     = (const float*)d_in[3];   // [4096][512] f32
  const int*   pseudo  = (const int*)d_in[4];     // [4096] i32

  char* ws = (char*)d_ws;
  unsigned char* fall  = (unsigned char*)(ws + OFF_FALL);
  unsigned*      cntP  = (unsigned*)(ws + OFF_CNTP);
  unsigned*      cntTP = (unsigned*)(ws + OFF_CNTTP);
  float*         Sacc  = (float*)(ws + OFF_S);
  float*         Pacc  = (float*)(ws + OFF_P);

  prep_k<<<dim3((NPAD * 32) / 256), 256, 0, stream>>>(centers, feats, ood, targets, pseudo,
                                                      fall, cntP, cntTP, Sacc);
  gemm_fused<<<dim3(NPAD / BN, NB / BM), 256, 0, stream>>>(fall, targets, pseudo, cntP, Sacc, Pacc);
  finalize_k<<<1, 256, 0, stream>>>(Sacc, Pacc, targets, cntTP, (float*)d_out);
}